// Round 1
// baseline (684.349 us; speedup 1.0000x reference)
//
#include <hip/hip_runtime.h>
#include <cstdint>
#include <cstddef>

#define T_TOTAL   131072
#define NWORDS    32768
#define WDIM      1024
#define CDIM      256
#define HID       512
#define NEMB      40
#define KDIM      1024
#define NDIM      1024

#define BM 128
#define BN 128
#define BK 32

typedef __attribute__((ext_vector_type(8))) short bf16x8;
typedef __attribute__((ext_vector_type(4))) float f32x4;
typedef __attribute__((ext_vector_type(4))) unsigned short u16x4;

__device__ __forceinline__ unsigned short f2bf(float x) {
  union { float f; unsigned int u; } v; v.f = x;
  unsigned int r = v.u + 0x7fffu + ((v.u >> 16) & 1u);   // RNE
  return (unsigned short)(r >> 16);
}
__device__ __forceinline__ float bf2f(unsigned short b) {
  union { float f; unsigned int u; } v; v.u = ((unsigned int)b) << 16;
  return v.f;
}

__device__ __forceinline__ void gld16(const void* src, void* lds) {
  __builtin_amdgcn_global_load_lds(
      (const __attribute__((address_space(1))) unsigned int*)src,
      (__attribute__((address_space(3))) unsigned int*)lds, 16, 0, 0);
}

// ---------------- index build ----------------
__global__ __launch_bounds__(256) void k_zero(int* __restrict__ p, int n) {
  int i = blockIdx.x * 256 + threadIdx.x;
  if (i < n) p[i] = 0;
}

__global__ __launch_bounds__(256) void k_hist(const int* __restrict__ wid,
                                              int* __restrict__ cnt) {
  int i = blockIdx.x * 256 + threadIdx.x;
  atomicAdd(&cnt[wid[i]], 1);
}

__global__ __launch_bounds__(1024) void k_scan(const int* __restrict__ cnt,
                                               int* __restrict__ offs,
                                               int* __restrict__ cur) {
  __shared__ int ps[1024];
  int tid = threadIdx.x;
  int base = tid * 32;
  int s = 0;
  for (int i = 0; i < 32; ++i) s += cnt[base + i];
  ps[tid] = s;
  __syncthreads();
  for (int d = 1; d < 1024; d <<= 1) {
    int add = (tid >= d) ? ps[tid - d] : 0;
    __syncthreads();
    ps[tid] += add;
    __syncthreads();
  }
  int run = (tid > 0) ? ps[tid - 1] : 0;
  for (int i = 0; i < 32; ++i) {
    int v = cnt[base + i];
    offs[base + i] = run;
    cur[base + i] = run;
    run += v;
  }
  if (tid == 1023) offs[NWORDS] = run;
}

__global__ __launch_bounds__(256) void k_scatter(const int* __restrict__ wid,
                                                 int* __restrict__ cur,
                                                 int* __restrict__ perm) {
  int i = blockIdx.x * 256 + threadIdx.x;
  int w = wid[i];
  int p = atomicAdd(&cur[w], 1);
  perm[p] = i;  // order within a word is nondeterministic; output values are not
}

// ---------------- Hc table: 40 x 1024 ----------------
// h = sigmoid(o)*tanh(sigmoid(i)*tanh(g)); Hc[e] = W_lin[:,1024:]@h + b_lin
__global__ __launch_bounds__(256) void k_prep_hc(const float* __restrict__ E,
                                                 const float* __restrict__ W_ih,
                                                 const float* __restrict__ b_ih,
                                                 const float* __restrict__ b_hh,
                                                 const float* __restrict__ W_lin,
                                                 const float* __restrict__ b_lin,
                                                 float* __restrict__ Hc) {
  int e = blockIdx.x;
  int tid = threadIdx.x;
  __shared__ float x[CDIM];
  __shared__ float h[HID];
  x[tid] = E[e * CDIM + tid];
  __syncthreads();
#pragma unroll
  for (int rep = 0; rep < 2; ++rep) {
    int j = rep * 256 + tid;                       // j in [0,512)
    float si = b_ih[j] + b_hh[j];                  // gate i: rows [0,512)
    float sg = b_ih[1024 + j] + b_hh[1024 + j];    // gate g: rows [1024,1536)
    float so = b_ih[1536 + j] + b_hh[1536 + j];    // gate o: rows [1536,2048)
    const float* wi = &W_ih[(size_t)j * CDIM];
    const float* wg = &W_ih[(size_t)(1024 + j) * CDIM];
    const float* wo = &W_ih[(size_t)(1536 + j) * CDIM];
    for (int k = 0; k < CDIM; ++k) {
      float xv = x[k];
      si += wi[k] * xv;
      sg += wg[k] * xv;
      so += wo[k] * xv;
    }
    float iv = 1.f / (1.f + expf(-si));
    float cv = iv * tanhf(sg);
    float ov = 1.f / (1.f + expf(-so));
    h[j] = ov * tanhf(cv);
  }
  __syncthreads();
#pragma unroll
  for (int rep = 0; rep < 4; ++rep) {
    int n = rep * 256 + tid;
    float s = b_lin[n];
    const float* wl = &W_lin[(size_t)n * 1536 + 1024];
    for (int k = 0; k < HID; ++k) s += wl[k] * h[k];
    Hc[e * NDIM + n] = s;
  }
}

// ---------------- fp32 -> (hi,lo) bf16 split, cols [0,1024) of a row-major mat ----------------
__global__ __launch_bounds__(256) void k_conv(const float* __restrict__ src, long ld,
                                              unsigned short* __restrict__ hi,
                                              unsigned short* __restrict__ lo) {
  long idx = ((long)blockIdx.x * 256 + threadIdx.x) * 4;
  long r = idx >> 10;
  int c = (int)(idx & 1023);
  const float4 v = *(const float4*)&src[r * ld + c];
  unsigned short h0 = f2bf(v.x), h1 = f2bf(v.y), h2 = f2bf(v.z), h3 = f2bf(v.w);
  u16x4 H = {h0, h1, h2, h3};
  u16x4 L = {f2bf(v.x - bf2f(h0)), f2bf(v.y - bf2f(h1)),
             f2bf(v.z - bf2f(h2)), f2bf(v.w - bf2f(h3))};
  *(u16x4*)&hi[idx] = H;
  *(u16x4*)&lo[idx] = L;
}

// ---------------- main GEMM (dedup'd words) + scatter epilogue ----------------
// P[m][n] = sum_k we[m][k] * W_lin[n][k]  via split-bf16 3-MFMA emulation.
// Epilogue: for each char t of word m: out[t] = relu(P[m] + Hc[char_ids[t]]).
template <bool PRECONV>
__global__ __launch_bounds__(256) void k_gemm_scatter(
    const float* __restrict__ Af,
    const unsigned short* __restrict__ Ah, const unsigned short* __restrict__ Al,
    const unsigned short* __restrict__ Bh, const unsigned short* __restrict__ Bl,
    const float* __restrict__ Hc, const int* __restrict__ offs,
    const int* __restrict__ perm, const int* __restrict__ cid,
    float* __restrict__ out) {
  __shared__ char sA[16384];   // PRECONV: [hi 8K][lo 8K] bf16; else fp32 128x32 swizzled
  __shared__ char sBh[8192];
  __shared__ char sBl[8192];

  int nwg = gridDim.x;
  int bid = blockIdx.x;
  int cpx = nwg >> 3;                       // XCD-contiguous swizzle (nwg % 8 == 0)
  int swz = (bid & 7) * cpx + (bid >> 3);
  int bn = swz & 7;                         // NDIM/BN == 8
  int bm = swz >> 3;

  int tid = threadIdx.x;
  int lane = tid & 63;
  int w = tid >> 6;
  int wm = w >> 1, wn = w & 1;
  int fr = lane & 15, fq = lane >> 4;
  int kb = fq * 8;                          // k-offset of this lane's 8 elems

  size_t arow0 = (size_t)bm * BM;
  size_t brow0 = (size_t)bn * BN;

  f32x4 acc[4][4];
#pragma unroll
  for (int i = 0; i < 4; ++i)
#pragma unroll
    for (int j = 0; j < 4; ++j) acc[i][j] = (f32x4)0.0f;

  for (int k0 = 0; k0 < KDIM; k0 += BK) {
    // ---- stage B hi/lo (bf16, 64B rows: bank-even without swizzle)
#pragma unroll
    for (int is = 0; is < 2; ++is) {
      int off = is * 4096 + tid * 16;
      int r = off >> 6;
      int col = (off & 63) >> 1;            // bf16 elems
      int ldsoff = is * 4096 + w * 1024;    // wave-uniform LDS base
      gld16(Bh + (brow0 + r) * KDIM + k0 + col, sBh + ldsoff);
      gld16(Bl + (brow0 + r) * KDIM + k0 + col, sBl + ldsoff);
    }
    // ---- stage A
    if (PRECONV) {
#pragma unroll
      for (int is = 0; is < 2; ++is) {
        int off = is * 4096 + tid * 16;
        int r = off >> 6;
        int col = (off & 63) >> 1;
        int ldsoff = is * 4096 + w * 1024;
        gld16(Ah + (arow0 + r) * KDIM + k0 + col, sA + ldsoff);
        gld16(Al + (arow0 + r) * KDIM + k0 + col, sA + 8192 + ldsoff);
      }
    } else {
      // fp32 tile: 128B rows -> 16-way conflict unless swizzled.
      // Linear LDS dest + inverse-swizzled global source; reads use same XOR.
#pragma unroll
      for (int is = 0; is < 4; ++is) {
        int off = is * 4096 + tid * 16;
        int r = off >> 7;
        int sl = (off >> 4) & 7;
        int col = ((sl ^ (r & 7)) << 2);    // floats
        int ldsoff = is * 4096 + w * 1024;
        gld16(Af + (arow0 + r) * KDIM + k0 + col, sA + ldsoff);
      }
    }
    __syncthreads();   // compiler drains vmcnt before s_barrier

    bf16x8 fah[4], fal[4], fbh[4], fbl[4];
#pragma unroll
    for (int ni = 0; ni < 4; ++ni) {
      int row = wn * 64 + ni * 16 + fr;
      fbh[ni] = *(const bf16x8*)(sBh + row * 64 + (kb << 1));
      fbl[ni] = *(const bf16x8*)(sBl + row * 64 + (kb << 1));
    }
    if (PRECONV) {
#pragma unroll
      for (int mi = 0; mi < 4; ++mi) {
        int row = wm * 64 + mi * 16 + fr;
        fah[mi] = *(const bf16x8*)(sA + row * 64 + (kb << 1));
        fal[mi] = *(const bf16x8*)(sA + 8192 + row * 64 + (kb << 1));
      }
    } else {
#pragma unroll
      for (int mi = 0; mi < 4; ++mi) {
        int row = wm * 64 + mi * 16 + fr;
        int s1 = (kb >> 2) ^ (row & 7);
        int s2 = ((kb >> 2) + 1) ^ (row & 7);
        float4 v1 = *(const float4*)(sA + row * 128 + s1 * 16);
        float4 v2 = *(const float4*)(sA + row * 128 + s2 * 16);
        float f[8] = {v1.x, v1.y, v1.z, v1.w, v2.x, v2.y, v2.z, v2.w};
        union { bf16x8 v; unsigned short u[8]; } H, L;
#pragma unroll
        for (int q = 0; q < 8; ++q) {
          unsigned short hq = f2bf(f[q]);
          H.u[q] = hq;
          L.u[q] = f2bf(f[q] - bf2f(hq));
        }
        fah[mi] = H.v;
        fal[mi] = L.v;
      }
    }

#pragma unroll
    for (int mi = 0; mi < 4; ++mi)
#pragma unroll
      for (int ni = 0; ni < 4; ++ni) {
        acc[mi][ni] = __builtin_amdgcn_mfma_f32_16x16x32_bf16(fah[mi], fbh[ni], acc[mi][ni], 0, 0, 0);
        acc[mi][ni] = __builtin_amdgcn_mfma_f32_16x16x32_bf16(fah[mi], fbl[ni], acc[mi][ni], 0, 0, 0);
        acc[mi][ni] = __builtin_amdgcn_mfma_f32_16x16x32_bf16(fal[mi], fbh[ni], acc[mi][ni], 0, 0, 0);
      }
    __syncthreads();
  }

  // ---- scatter epilogue: C/D layout col = lane&15, row = (lane>>4)*4 + reg
  int colbase = (int)brow0 + wn * 64 + fr;
#pragma unroll
  for (int mi = 0; mi < 4; ++mi) {
#pragma unroll
    for (int j = 0; j < 4; ++j) {
      int m = (int)arow0 + wm * 64 + mi * 16 + fq * 4 + j;
      int beg = offs[m];
      int end = offs[m + 1];
      float v0 = acc[mi][0][j], v1 = acc[mi][1][j], v2 = acc[mi][2][j], v3 = acc[mi][3][j];
      for (int p = beg; p < end; ++p) {
        int t = perm[p];
        int c = cid[t];
        const float* hc = &Hc[(size_t)c * NDIM + colbase];
        float* dst = &out[(size_t)t * NDIM + colbase];
        dst[0]  = fmaxf(v0 + hc[0], 0.f);
        dst[16] = fmaxf(v1 + hc[16], 0.f);
        dst[32] = fmaxf(v2 + hc[32], 0.f);
        dst[48] = fmaxf(v3 + hc[48], 0.f);
      }
    }
  }
}

extern "C" void kernel_launch(void* const* d_in, const int* in_sizes, int n_in,
                              void* d_out, int out_size, void* d_ws, size_t ws_size,
                              hipStream_t stream) {
  (void)in_sizes; (void)n_in; (void)out_size;
  const float* word_emb = (const float*)d_in[0];
  const int*   char_ids = (const int*)d_in[1];
  const int*   word_ids = (const int*)d_in[2];
  const float* E        = (const float*)d_in[3];
  const float* W_ih     = (const float*)d_in[4];
  const float* b_ih     = (const float*)d_in[5];
  const float* b_hh     = (const float*)d_in[6];
  const float* W_lin    = (const float*)d_in[7];
  const float* b_lin    = (const float*)d_in[8];
  float* out = (float*)d_out;
  char* ws = (char*)d_ws;

  size_t o = 0;
  auto alloc = [&](size_t b) { size_t r = o; o = (o + b + 255) & ~(size_t)255; return r; };
  size_t oHc   = alloc((size_t)NEMB * NDIM * 4);
  size_t oBh   = alloc((size_t)NDIM * KDIM * 2);
  size_t oBl   = alloc((size_t)NDIM * KDIM * 2);
  size_t oCnt  = alloc((size_t)NWORDS * 4);
  size_t oOffs = alloc((size_t)(NWORDS + 1) * 4);
  size_t oCur  = alloc((size_t)NWORDS * 4);
  size_t oPerm = alloc((size_t)T_TOTAL * 4);
  size_t oAh   = alloc((size_t)NWORDS * KDIM * 2);
  size_t oAl   = alloc((size_t)NWORDS * KDIM * 2);
  size_t needA = o;

  float* Hc          = (float*)(ws + oHc);
  unsigned short* Bh = (unsigned short*)(ws + oBh);
  unsigned short* Bl = (unsigned short*)(ws + oBl);
  int* cnt   = (int*)(ws + oCnt);
  int* offsp = (int*)(ws + oOffs);
  int* cur   = (int*)(ws + oCur);
  int* perm  = (int*)(ws + oPerm);
  unsigned short* Ah = (unsigned short*)(ws + oAh);
  unsigned short* Al = (unsigned short*)(ws + oAl);

  bool preconv = (ws_size >= needA);

  // inverted index word -> char positions
  k_zero<<<(NWORDS + 255) / 256, 256, 0, stream>>>(cnt, NWORDS);
  k_hist<<<T_TOTAL / 256, 256, 0, stream>>>(word_ids, cnt);
  k_scan<<<1, 1024, 0, stream>>>(cnt, offsp, cur);
  k_scatter<<<T_TOTAL / 256, 256, 0, stream>>>(word_ids, cur, perm);

  // LSTM-branch table + W1 split
  k_prep_hc<<<NEMB, 256, 0, stream>>>(E, W_ih, b_ih, b_hh, W_lin, b_lin, Hc);
  k_conv<<<(NDIM * KDIM / 4) / 256, 256, 0, stream>>>(W_lin, 1536L, Bh, Bl);

  int grid = (NWORDS / BM) * (NDIM / BN);  // 2048
  if (preconv) {
    k_conv<<<((size_t)NWORDS * KDIM / 4) / 256, 256, 0, stream>>>(word_emb, 1024L, Ah, Al);
    k_gemm_scatter<true><<<grid, 256, 0, stream>>>(
        word_emb, Ah, Al, Bh, Bl, Hc, offsp, perm, char_ids, out);
  } else {
    k_gemm_scatter<false><<<grid, 256, 0, stream>>>(
        word_emb, Ah, Al, Bh, Bl, Hc, offsp, perm, char_ids, out);
  }
}

// Round 2
// 602.301 us; speedup vs baseline: 1.1362x; 1.1362x over previous
//
#include <hip/hip_runtime.h>
#include <cstdint>
#include <cstddef>

#define T_TOTAL   131072
#define NWORDS    32768
#define WDIM      1024
#define CDIM      256
#define HID       512
#define NEMB      40
#define KDIM      1024
#define NDIM      1024

#define BM 128
#define BN 128
#define BK 32
#define EPS 132   // epilogue LDS row stride (floats): 132*4=528B -> bank-even

typedef __attribute__((ext_vector_type(8))) short bf16x8;
typedef __attribute__((ext_vector_type(4))) float f32x4;
typedef __attribute__((ext_vector_type(4))) unsigned short u16x4;

__device__ __forceinline__ unsigned short f2bf(float x) {
  union { float f; unsigned int u; } v; v.f = x;
  unsigned int r = v.u + 0x7fffu + ((v.u >> 16) & 1u);   // RNE
  return (unsigned short)(r >> 16);
}
__device__ __forceinline__ float bf2f(unsigned short b) {
  union { float f; unsigned int u; } v; v.u = ((unsigned int)b) << 16;
  return v.f;
}

__device__ __forceinline__ void gld16(const void* src, void* lds) {
  __builtin_amdgcn_global_load_lds(
      (const __attribute__((address_space(1))) unsigned int*)src,
      (__attribute__((address_space(3))) unsigned int*)lds, 16, 0, 0);
}

__device__ __forceinline__ void nt_store_f2(float* p, float a, float b) {
  union { float f[2]; unsigned long long u; } v;
  v.f[0] = a; v.f[1] = b;
  __builtin_nontemporal_store(v.u, (unsigned long long*)p);
}

// ---------------- index build ----------------
__global__ __launch_bounds__(256) void k_zero(int* __restrict__ p, int n) {
  int i = blockIdx.x * 256 + threadIdx.x;
  if (i < n) p[i] = 0;
}

__global__ __launch_bounds__(256) void k_hist(const int* __restrict__ wid,
                                              int* __restrict__ cnt) {
  int i = blockIdx.x * 256 + threadIdx.x;
  atomicAdd(&cnt[wid[i]], 1);
}

__global__ __launch_bounds__(1024) void k_scan(const int* __restrict__ cnt,
                                               int* __restrict__ offs,
                                               int* __restrict__ cur) {
  __shared__ int ps[1024];
  int tid = threadIdx.x;
  int base = tid * 32;
  int s = 0;
  for (int i = 0; i < 32; ++i) s += cnt[base + i];
  ps[tid] = s;
  __syncthreads();
  for (int d = 1; d < 1024; d <<= 1) {
    int add = (tid >= d) ? ps[tid - d] : 0;
    __syncthreads();
    ps[tid] += add;
    __syncthreads();
  }
  int run = (tid > 0) ? ps[tid - 1] : 0;
  for (int i = 0; i < 32; ++i) {
    int v = cnt[base + i];
    offs[base + i] = run;
    cur[base + i] = run;
    run += v;
  }
  if (tid == 1023) offs[NWORDS] = run;
}

__global__ __launch_bounds__(256) void k_scatter(const int* __restrict__ wid,
                                                 int* __restrict__ cur,
                                                 int* __restrict__ perm) {
  int i = blockIdx.x * 256 + threadIdx.x;
  int w = wid[i];
  int p = atomicAdd(&cur[w], 1);
  perm[p] = i;  // order within a word is nondeterministic; output values are not
}

// ---------------- LSTM h table: 40 x 512 ----------------
__global__ __launch_bounds__(256) void k_prep_h(const float* __restrict__ E,
                                                const float* __restrict__ W_ih,
                                                const float* __restrict__ b_ih,
                                                const float* __restrict__ b_hh,
                                                float* __restrict__ h) {
  int e = blockIdx.x;
  int tid = threadIdx.x;
  __shared__ float x[CDIM];
  x[tid] = E[e * CDIM + tid];
  __syncthreads();
  const float4* xv = (const float4*)x;
#pragma unroll
  for (int rep = 0; rep < 2; ++rep) {
    int j = rep * 256 + tid;                       // j in [0,512)
    float si = b_ih[j] + b_hh[j];
    float sg = b_ih[1024 + j] + b_hh[1024 + j];
    float so = b_ih[1536 + j] + b_hh[1536 + j];
    const float4* wi = (const float4*)&W_ih[(size_t)j * CDIM];
    const float4* wg = (const float4*)&W_ih[(size_t)(1024 + j) * CDIM];
    const float4* wo = (const float4*)&W_ih[(size_t)(1536 + j) * CDIM];
    for (int k = 0; k < CDIM / 4; ++k) {
      float4 d = xv[k];
      float4 a = wi[k]; si += a.x*d.x + a.y*d.y + a.z*d.z + a.w*d.w;
      float4 b = wg[k]; sg += b.x*d.x + b.y*d.y + b.z*d.z + b.w*d.w;
      float4 c = wo[k]; so += c.x*d.x + c.y*d.y + c.z*d.z + c.w*d.w;
    }
    float iv = 1.f / (1.f + expf(-si));
    float cv = iv * tanhf(sg);
    float ov = 1.f / (1.f + expf(-so));
    h[e * HID + j] = ov * tanhf(cv);
  }
}

// ---------------- Hc table: 40 x 1024 = W_lin[:,1024:] @ h + b_lin ----------------
__global__ __launch_bounds__(256) void k_prep_hc2(const float* __restrict__ h,
                                                  const float* __restrict__ W_lin,
                                                  const float* __restrict__ b_lin,
                                                  float* __restrict__ Hc) {
  int e = blockIdx.x >> 2;
  int chunk = blockIdx.x & 3;
  int tid = threadIdx.x;
  __shared__ float hs[HID];
  hs[tid] = h[e * HID + tid];
  hs[256 + tid] = h[e * HID + 256 + tid];
  __syncthreads();
  int n = chunk * 256 + tid;
  float s = b_lin[n];
  const float4* wl = (const float4*)&W_lin[(size_t)n * 1536 + 1024];
  const float4* hv = (const float4*)hs;
  for (int k = 0; k < HID / 4; ++k) {
    float4 a = wl[k], b = hv[k];
    s += a.x*b.x + a.y*b.y + a.z*b.z + a.w*b.w;
  }
  Hc[e * NDIM + n] = s;
}

// ---------------- fp32 -> (hi,lo) bf16 split, cols [0,1024) of a row-major mat ----------------
__global__ __launch_bounds__(256) void k_conv(const float* __restrict__ src, long ld,
                                              unsigned short* __restrict__ hi,
                                              unsigned short* __restrict__ lo) {
  long idx = ((long)blockIdx.x * 256 + threadIdx.x) * 4;
  long r = idx >> 10;
  int c = (int)(idx & 1023);
  const float4 v = *(const float4*)&src[r * ld + c];
  unsigned short h0 = f2bf(v.x), h1 = f2bf(v.y), h2 = f2bf(v.z), h3 = f2bf(v.w);
  u16x4 H = {h0, h1, h2, h3};
  u16x4 L = {f2bf(v.x - bf2f(h0)), f2bf(v.y - bf2f(h1)),
             f2bf(v.z - bf2f(h2)), f2bf(v.w - bf2f(h3))};
  *(u16x4*)&hi[idx] = H;
  *(u16x4*)&lo[idx] = L;
}

// ---------------- main GEMM (dedup'd words) + coalesced scatter epilogue ----------------
// P[m][n] = sum_k we[m][k] * W_lin[n][k]  via split-bf16 3-MFMA emulation.
// Epilogue: stage P tile in LDS; per char t of word m: out[t] = relu(P[m] + Hc[cid[t]]),
// written as wave-cooperative float2 rows (512B coalesced nontemporal stores).
template <bool PRECONV>
__global__ __launch_bounds__(256) void k_gemm_scatter(
    const float* __restrict__ Af,
    const unsigned short* __restrict__ Ah, const unsigned short* __restrict__ Al,
    const unsigned short* __restrict__ Bh, const unsigned short* __restrict__ Bl,
    const float* __restrict__ Hc, const int* __restrict__ offs,
    const int* __restrict__ perm, const int* __restrict__ cid,
    float* __restrict__ out) {
  // GEMM phase layout: sA = smem[0,16K), sBh = smem[16K,24K), sBl = smem[24K,32K)
  // Epilogue overlay: ep = 64 x EPS floats (33792 B)
  __shared__ __align__(16) char smem[64 * EPS * 4];
  char* sA  = smem;
  char* sBh = smem + 16384;
  char* sBl = smem + 24576;

  int nwg = gridDim.x;
  int bid = blockIdx.x;
  int cpx = nwg >> 3;                       // XCD-contiguous swizzle (nwg % 8 == 0)
  int swz = (bid & 7) * cpx + (bid >> 3);
  int bn = swz & 7;                         // NDIM/BN == 8
  int bm = swz >> 3;

  int tid = threadIdx.x;
  int lane = tid & 63;
  int w = tid >> 6;
  int wm = w >> 1, wn = w & 1;
  int fr = lane & 15, fq = lane >> 4;
  int kb = fq * 8;                          // k-offset of this lane's 8 elems

  size_t arow0 = (size_t)bm * BM;
  size_t brow0 = (size_t)bn * BN;

  f32x4 acc[4][4];
#pragma unroll
  for (int i = 0; i < 4; ++i)
#pragma unroll
    for (int j = 0; j < 4; ++j) acc[i][j] = (f32x4)0.0f;

  for (int k0 = 0; k0 < KDIM; k0 += BK) {
    // ---- stage B hi/lo (bf16, 64B rows: bank-even without swizzle)
#pragma unroll
    for (int is = 0; is < 2; ++is) {
      int off = is * 4096 + tid * 16;
      int r = off >> 6;
      int col = (off & 63) >> 1;            // bf16 elems
      int ldsoff = is * 4096 + w * 1024;    // wave-uniform LDS base
      gld16(Bh + (brow0 + r) * KDIM + k0 + col, sBh + ldsoff);
      gld16(Bl + (brow0 + r) * KDIM + k0 + col, sBl + ldsoff);
    }
    // ---- stage A
    if (PRECONV) {
#pragma unroll
      for (int is = 0; is < 2; ++is) {
        int off = is * 4096 + tid * 16;
        int r = off >> 6;
        int col = (off & 63) >> 1;
        int ldsoff = is * 4096 + w * 1024;
        gld16(Ah + (arow0 + r) * KDIM + k0 + col, sA + ldsoff);
        gld16(Al + (arow0 + r) * KDIM + k0 + col, sA + 8192 + ldsoff);
      }
    } else {
      // fp32 tile: 128B rows -> swizzled (linear LDS dest + inverse-swizzled source)
#pragma unroll
      for (int is = 0; is < 4; ++is) {
        int off = is * 4096 + tid * 16;
        int r = off >> 7;
        int sl = (off >> 4) & 7;
        int col = ((sl ^ (r & 7)) << 2);    // floats
        int ldsoff = is * 4096 + w * 1024;
        gld16(Af + (arow0 + r) * KDIM + k0 + col, sA + ldsoff);
      }
    }
    __syncthreads();   // compiler drains vmcnt before s_barrier

    bf16x8 fah[4], fal[4], fbh[4], fbl[4];
#pragma unroll
    for (int ni = 0; ni < 4; ++ni) {
      int row = wn * 64 + ni * 16 + fr;
      fbh[ni] = *(const bf16x8*)(sBh + row * 64 + (kb << 1));
      fbl[ni] = *(const bf16x8*)(sBl + row * 64 + (kb << 1));
    }
    if (PRECONV) {
#pragma unroll
      for (int mi = 0; mi < 4; ++mi) {
        int row = wm * 64 + mi * 16 + fr;
        fah[mi] = *(const bf16x8*)(sA + row * 64 + (kb << 1));
        fal[mi] = *(const bf16x8*)(sA + 8192 + row * 64 + (kb << 1));
      }
    } else {
#pragma unroll
      for (int mi = 0; mi < 4; ++mi) {
        int row = wm * 64 + mi * 16 + fr;
        int s1 = (kb >> 2) ^ (row & 7);
        int s2 = ((kb >> 2) + 1) ^ (row & 7);
        float4 v1 = *(const float4*)(sA + row * 128 + s1 * 16);
        float4 v2 = *(const float4*)(sA + row * 128 + s2 * 16);
        float f[8] = {v1.x, v1.y, v1.z, v1.w, v2.x, v2.y, v2.z, v2.w};
        union { bf16x8 v; unsigned short u[8]; } H, L;
#pragma unroll
        for (int q = 0; q < 8; ++q) {
          unsigned short hq = f2bf(f[q]);
          H.u[q] = hq;
          L.u[q] = f2bf(f[q] - bf2f(hq));
        }
        fah[mi] = H.v;
        fal[mi] = L.v;
      }
    }

#pragma unroll
    for (int mi = 0; mi < 4; ++mi)
#pragma unroll
      for (int ni = 0; ni < 4; ++ni) {
        acc[mi][ni] = __builtin_amdgcn_mfma_f32_16x16x32_bf16(fah[mi], fbh[ni], acc[mi][ni], 0, 0, 0);
        acc[mi][ni] = __builtin_amdgcn_mfma_f32_16x16x32_bf16(fah[mi], fbl[ni], acc[mi][ni], 0, 0, 0);
        acc[mi][ni] = __builtin_amdgcn_mfma_f32_16x16x32_bf16(fal[mi], fbh[ni], acc[mi][ni], 0, 0, 0);
      }
    __syncthreads();
  }

  // ---- epilogue: stage P into LDS (two 64-row halves), coalesced scatter
  // C/D frag layout: row = wm*64 + mi*16 + fq*4 + j, col = wn*64 + ni*16 + fr
  float* ep = (float*)smem;
#pragma unroll
  for (int half = 0; half < 2; ++half) {
    if (wm == half) {
#pragma unroll
      for (int mi = 0; mi < 4; ++mi)
#pragma unroll
        for (int ni = 0; ni < 4; ++ni)
#pragma unroll
          for (int j = 0; j < 4; ++j) {
            int r = mi * 16 + fq * 4 + j;
            int c = wn * 64 + ni * 16 + fr;
            ep[r * EPS + c] = acc[mi][ni][j];
          }
    }
    __syncthreads();
    // rows [half*64, half*64+64): wave w handles rows w, w+4, ...
    for (int m = w; m < 64; m += 4) {
      int gm = (int)arow0 + half * 64 + m;
      int beg = offs[gm];
      int end = offs[gm + 1];
      if (beg == end) continue;
      float2 pv = *(const float2*)&ep[m * EPS + lane * 2];
      for (int p = beg; p < end; ++p) {
        int t = perm[p];
        int c = cid[t];
        float2 hv = *(const float2*)&Hc[(size_t)c * NDIM + brow0 + lane * 2];
        nt_store_f2(&out[(size_t)t * NDIM + brow0 + lane * 2],
                    fmaxf(pv.x + hv.x, 0.f), fmaxf(pv.y + hv.y, 0.f));
      }
    }
    __syncthreads();
  }
}

extern "C" void kernel_launch(void* const* d_in, const int* in_sizes, int n_in,
                              void* d_out, int out_size, void* d_ws, size_t ws_size,
                              hipStream_t stream) {
  (void)in_sizes; (void)n_in; (void)out_size;
  const float* word_emb = (const float*)d_in[0];
  const int*   char_ids = (const int*)d_in[1];
  const int*   word_ids = (const int*)d_in[2];
  const float* E        = (const float*)d_in[3];
  const float* W_ih     = (const float*)d_in[4];
  const float* b_ih     = (const float*)d_in[5];
  const float* b_hh     = (const float*)d_in[6];
  const float* W_lin    = (const float*)d_in[7];
  const float* b_lin    = (const float*)d_in[8];
  float* out = (float*)d_out;
  char* ws = (char*)d_ws;

  size_t o = 0;
  auto alloc = [&](size_t b) { size_t r = o; o = (o + b + 255) & ~(size_t)255; return r; };
  size_t oHc   = alloc((size_t)NEMB * NDIM * 4);
  size_t oH    = alloc((size_t)NEMB * HID * 4);
  size_t oBh   = alloc((size_t)NDIM * KDIM * 2);
  size_t oBl   = alloc((size_t)NDIM * KDIM * 2);
  size_t oCnt  = alloc((size_t)NWORDS * 4);
  size_t oOffs = alloc((size_t)(NWORDS + 1) * 4);
  size_t oCur  = alloc((size_t)NWORDS * 4);
  size_t oPerm = alloc((size_t)T_TOTAL * 4);
  size_t oAh   = alloc((size_t)NWORDS * KDIM * 2);
  size_t oAl   = alloc((size_t)NWORDS * KDIM * 2);
  size_t needA = o;

  float* Hc          = (float*)(ws + oHc);
  float* hbuf        = (float*)(ws + oH);
  unsigned short* Bh = (unsigned short*)(ws + oBh);
  unsigned short* Bl = (unsigned short*)(ws + oBl);
  int* cnt   = (int*)(ws + oCnt);
  int* offsp = (int*)(ws + oOffs);
  int* cur   = (int*)(ws + oCur);
  int* perm  = (int*)(ws + oPerm);
  unsigned short* Ah = (unsigned short*)(ws + oAh);
  unsigned short* Al = (unsigned short*)(ws + oAl);

  bool preconv = (ws_size >= needA);

  // inverted index word -> char positions
  k_zero<<<(NWORDS + 255) / 256, 256, 0, stream>>>(cnt, NWORDS);
  k_hist<<<T_TOTAL / 256, 256, 0, stream>>>(word_ids, cnt);
  k_scan<<<1, 1024, 0, stream>>>(cnt, offsp, cur);
  k_scatter<<<T_TOTAL / 256, 256, 0, stream>>>(word_ids, cur, perm);

  // LSTM-branch table + W1 split
  k_prep_h<<<NEMB, 256, 0, stream>>>(E, W_ih, b_ih, b_hh, hbuf);
  k_prep_hc2<<<NEMB * 4, 256, 0, stream>>>(hbuf, W_lin, b_lin, Hc);
  k_conv<<<(NDIM * KDIM / 4) / 256, 256, 0, stream>>>(W_lin, 1536L, Bh, Bl);

  int grid = (NWORDS / BM) * (NDIM / BN);  // 2048
  if (preconv) {
    k_conv<<<((size_t)NWORDS * KDIM / 4) / 256, 256, 0, stream>>>(word_emb, 1024L, Ah, Al);
    k_gemm_scatter<true><<<grid, 256, 0, stream>>>(
        word_emb, Ah, Al, Bh, Bl, Hc, offsp, perm, char_ids, out);
  } else {
    k_gemm_scatter<false><<<grid, 256, 0, stream>>>(
        word_emb, Ah, Al, Bh, Bl, Hc, offsp, perm, char_ids, out);
  }
}